// Round 1
// baseline (99.824 us; speedup 1.0000x reference)
//
#include <hip/hip_runtime.h>

// EntropyPatcher: B=256 rows, L=8192 tokens in [0,5), E=64.
// out = concat(blt_features[B,E], entropy[B,L]) as float32.
//
// Key identity: blt = (sum_valid relu(mean*w1+b1) / P) @ w2^T + b2
// so we never materialize [B,MAXP,E].
//
// One block (256 thr) per row. Sequential patch walk parallelized by
// chunk decomposition: jumps are 3 or 12 (<=12), so entry offset into any
// 128-chunk is 0..11; precompute exit[chunk][entry] in parallel, compose.

constexpr int B_ = 256;
constexpr int L_ = 8192;
constexpr int E_ = 64;
constexpr int CHUNK = 128;
constexpr int NCH = L_ / CHUNK;   // 64
constexpr int MAXPC = 44;         // ceil(128/3)=43 max patches/chunk, +1 pad

__global__ __launch_bounds__(256, 1)
void entropy_patcher_kernel(const int* __restrict__ x,
                            const float* __restrict__ w1,
                            const float* __restrict__ b1,
                            const float* __restrict__ w2,
                            const float* __restrict__ b2,
                            float* __restrict__ dout) {
  // codesPad: u32 one-hot codes (padded +4 each side) during entropy phase;
  // reused afterwards as float cs[L+1] exclusive token prefix sums.
  __shared__ __align__(16) unsigned int codesPad[L_ + 8];
  __shared__ __align__(16) unsigned char tok8[L_];
  __shared__ unsigned long long maskS[L_ / 64];      // bit i: ent[i] > THR
  __shared__ __align__(16) float meanbuf[NCH][MAXPC];
  __shared__ unsigned char exitT[NCH][12];
  __shared__ unsigned char offC[NCH];
  __shared__ int cntC[NCH];
  __shared__ int waveTot[4];
  __shared__ float Sred[4][E_];
  __shared__ float partG[4][E_];
  __shared__ float avgv[E_];
  __shared__ float rcpTab[16];
  __shared__ int Pcount;

  const int tid  = threadIdx.x;
  const int lane = tid & 63;
  const int wv   = tid >> 6;
  const int b    = blockIdx.x;

  const int* xr = x + b * L_;
  float* entOut = dout + (size_t)B_ * E_ + (size_t)b * L_;

  // ---------- Phase A: stage tokens (bytes) + one-hot codes into LDS ----------
  if (tid < 16) rcpTab[tid] = 1.0f / (float)(tid < 1 ? 1 : tid);
  if (tid < 4) { codesPad[tid] = 0u; codesPad[4 + L_ + tid] = 0u; }
  #pragma unroll
  for (int k = 0; k < 8; ++k) {
    int g = tid + 256 * k;                 // dword-group index, 4 tokens each
    int4 v = ((const int4*)xr)[g];         // 16B coalesced
    unsigned t0 = (unsigned)v.x, t1 = (unsigned)v.y;
    unsigned t2 = (unsigned)v.z, t3 = (unsigned)v.w;
    ((unsigned*)tok8)[g] = t0 | (t1 << 8) | (t2 << 16) | (t3 << 24);
    unsigned c0 = t0 > 4u ? 4u : t0, c1 = t1 > 4u ? 4u : t1;
    unsigned c2 = t2 > 4u ? 4u : t2, c3 = t3 > 4u ? 4u : t3;
    uint4 cv;
    cv.x = 1u << (6 * c0); cv.y = 1u << (6 * c1);
    cv.z = 1u << (6 * c2); cv.w = 1u << (6 * c3);
    ((uint4*)(codesPad + 4))[g] = cv;      // dense b128 LDS writes
  }
  __syncthreads();

  // ---------- Phase B: windowed entropy + decision bitmask ----------
  for (int k = 0; k < 32; ++k) {
    int p = tid + 256 * k;
    unsigned s = 0;                         // 5 class counts in 6-bit fields
    #pragma unroll
    for (int j = 0; j < 9; ++j) s += codesPad[p + j];   // window [p-4,p+4], pads are 0
    float rT = 1.0f / 9.0f;
    if (p < 4 || p > L_ - 5) {              // edge: total = clipped window size
      int lo = p - 4; if (lo < 0) lo = 0;
      int hi = p + 4; if (hi > L_ - 1) hi = L_ - 1;
      rT = 1.0f / (float)(hi - lo + 1);
    }
    float ent = 0.0f;
    #pragma unroll
    for (int cc = 0; cc < 5; ++cc) {
      float pr = (float)((s >> (6 * cc)) & 63u) * rT;
      ent -= pr * __log2f(pr + 1e-12f);     // pr=0 -> 0 * finite = 0, matches ref eps
    }
    entOut[p] = ent;                        // coalesced 256B per wave
    unsigned long long bal = __ballot(ent > 1.5f);  // word index p>>6 is wave-uniform
    if (lane == 0) maskS[(unsigned)p >> 6] = bal;
  }
  __syncthreads();

  // ---------- Phase C: exclusive prefix sum of tokens -> cs[0..L] (exact ints) ----------
  {
    uint4 a0 = ((const uint4*)tok8)[2 * tid];
    uint4 a1 = ((const uint4*)tok8)[2 * tid + 1];
    unsigned wd[8] = {a0.x, a0.y, a0.z, a0.w, a1.x, a1.y, a1.z, a1.w};
    int tv[32];
    int localSum = 0;
    #pragma unroll
    for (int j = 0; j < 32; ++j) {
      tv[j] = (int)((wd[j >> 2] >> (8 * (j & 3))) & 0xffu);
      localSum += tv[j];
    }
    int v = localSum;                       // wave inclusive scan
    #pragma unroll
    for (int d = 1; d < 64; d <<= 1) {
      int t = __shfl_up(v, d, 64);
      if (lane >= d) v += t;
    }
    if (lane == 63) waveTot[wv] = v;
    __syncthreads();
    int base = 0;
    for (int q = 0; q < wv; ++q) base += waveTot[q];
    float* cs = (float*)codesPad;           // overwrite codes (dead after B)
    float acc = (float)(base + v - localSum);   // exclusive prefix before 32*tid
    float4* csv = (float4*)cs;
    #pragma unroll
    for (int j4 = 0; j4 < 8; ++j4) {
      float4 f;
      f.x = acc; acc += (float)tv[4 * j4 + 0];
      f.y = acc; acc += (float)tv[4 * j4 + 1];
      f.z = acc; acc += (float)tv[4 * j4 + 2];
      f.w = acc; acc += (float)tv[4 * j4 + 3];
      csv[8 * tid + j4] = f;
    }
    if (tid == 255) cs[L_] = acc;           // total sum
  }
  __syncthreads();

  // ---------- Phase D: per-(chunk, entry-offset) exit table, then compose ----------
  #pragma unroll
  for (int jj = 0; jj < 3; ++jj) {          // 768 jobs / 256 threads
    int c = lane;                           // note: c = tid & 63
    int o = wv + 4 * jj;                    // 0..11
    int p = c * CHUNK + o;
    int end = c * CHUNK + CHUNK;
    while (p < end) {
      int bit = (int)((maskS[p >> 6] >> (p & 63)) & 1ULL);
      p += bit ? 3 : 12;
    }
    exitT[c][o] = (unsigned char)(p - end); // 0..11
  }
  __syncthreads();
  if (tid == 0) {
    unsigned char o = 0;
    for (int c = 0; c < NCH; ++c) { offC[c] = o; o = exitT[c][o]; }
  }
  __syncthreads();

  // ---------- Phase E: 64 chunk-walkers emit patch means ----------
  if (tid < NCH) {
    const float* cs = (const float*)codesPad;
    int c = tid;
    int p = c * CHUNK + (int)offC[c];
    int end = c * CHUNK + CHUNK;            // == L for c=63
    int n = 0;
    while (p < end) {
      int bit = (int)((maskS[p >> 6] >> (p & 63)) & 1ULL);
      int ps = bit ? 3 : 12;
      int j = p + ps; if (j > L_) j = L_;
      float num = cs[j] - cs[p];            // exact integer difference
      meanbuf[c][n++] = num * rcpTab[j - p];
      p += ps;
    }
    cntC[c] = n;
  }
  __syncthreads();

  // ---------- Phase F: S[e] = sum over patches of relu(mean*w1[e]+b1[e]) ----------
  if (tid == 0) {
    int P = 0;
    #pragma unroll
    for (int c = 0; c < NCH; ++c) P += cntC[c];
    Pcount = P;
  }
  {
    float w1v = w1[lane];
    float b1v = b1[lane];
    float S = 0.0f;
    for (int c = wv; c < NCH; c += 4) {     // wave w takes chunks w, w+4, ...
      int n = cntC[c];
      const float* mb = &meanbuf[c][0];
      int j = 0;
      for (; j + 4 <= n; j += 4) {
        float4 m4 = *((const float4*)(mb + j));   // broadcast b128 read
        S += fmaxf(fmaf(m4.x, w1v, b1v), 0.0f);
        S += fmaxf(fmaf(m4.y, w1v, b1v), 0.0f);
        S += fmaxf(fmaf(m4.z, w1v, b1v), 0.0f);
        S += fmaxf(fmaf(m4.w, w1v, b1v), 0.0f);
      }
      for (; j < n; ++j)
        S += fmaxf(fmaf(mb[j], w1v, b1v), 0.0f);
    }
    Sred[wv][lane] = S;
  }
  __syncthreads();

  // ---------- Phase G: avg -> tiny matvec (w2 is L2-resident, 16KB) ----------
  if (tid < E_) {
    float s = Sred[0][tid] + Sred[1][tid] + Sred[2][tid] + Sred[3][tid];
    avgv[tid] = s / (float)Pcount;
  }
  __syncthreads();
  {
    int e = lane, q = wv;                   // each wave does 16 of the 64 k's
    float acc = 0.0f;
    #pragma unroll
    for (int kk = 0; kk < 16; ++kk) {
      int k = 16 * q + kk;
      acc = fmaf(avgv[k], w2[e * 64 + k], acc);
    }
    partG[q][e] = acc;
  }
  __syncthreads();
  if (tid < E_) {
    float r = partG[0][tid] + partG[1][tid] + partG[2][tid] + partG[3][tid] + b2[tid];
    dout[(size_t)b * E_ + tid] = r;
  }
}

extern "C" void kernel_launch(void* const* d_in, const int* in_sizes, int n_in,
                              void* d_out, int out_size, void* d_ws, size_t ws_size,
                              hipStream_t stream) {
  const int*   x  = (const int*)d_in[0];
  const float* w1 = (const float*)d_in[1];
  const float* b1 = (const float*)d_in[2];
  const float* w2 = (const float*)d_in[3];
  const float* b2 = (const float*)d_in[4];
  float* out = (float*)d_out;
  entropy_patcher_kernel<<<B_, 256, 0, stream>>>(x, w1, b1, w2, b2, out);
}

// Round 2
// 82.685 us; speedup vs baseline: 1.2073x; 1.2073x over previous
//
#include <hip/hip_runtime.h>
#include <math.h>

// EntropyPatcher: B=256 rows, L=8192 tokens in [0,5), E=64.
// out = concat(blt_features[B,E], entropy[B,L]) as float32.
// Identity: blt = (sum_patches relu(mean*w1+b1) / P) @ w2^T + b2.
//
// One block of 1024 threads (16 waves) per row, 256 blocks = 1/CU.
// Entropy: register sliding window + 100-entry pair table (no v_log in hot path).
// Patch walk: per-chunk (128 tok) exit tables walked with masks in VGPRs,
// composed via packed-nibble function-composition shuffle scan.

constexpr int B_ = 256;
constexpr int L_ = 8192;
constexpr int E_ = 64;
constexpr int T_ = 1024;     // threads/block (16 waves)
constexpr int PT = 8;        // positions per thread
constexpr int CHUNK = 128;
constexpr int NCH = L_ / CHUNK;  // 64
constexpr int MAXPC = 44;        // ceil(128/3)=43 max patches/chunk (+1 pad)

__global__ __launch_bounds__(1024)
void entropy_patcher_kernel(const int* __restrict__ x,
                            const float* __restrict__ w1,
                            const float* __restrict__ b1,
                            const float* __restrict__ w2,
                            const float* __restrict__ b2,
                            float* __restrict__ dout) {
  __shared__ __align__(16) unsigned char tok8p[8 + L_ + 8];  // 0xFF sentinel pads
  __shared__ __align__(16) float csBuf[L_ + 4];              // cs[0..L]
  __shared__ __align__(16) float meanbuf[NCH][MAXPC];
  __shared__ __align__(16) float pairTab[100];               // f(a)+f(b), total=9
  __shared__ __align__(16) unsigned char maskBytes[T_];      // bit p: ent[p] > 1.5
  __shared__ unsigned char exitT[NCH][12];
  __shared__ float rcpTab[13];
  __shared__ int cntC[NCH];
  __shared__ int waveTot[16];
  __shared__ float Sred[16][E_];
  __shared__ float partG[16][E_];
  __shared__ float avgv[E_];
  __shared__ int PcountS;

  const int tid  = threadIdx.x;
  const int lane = tid & 63;
  const int wv   = tid >> 6;
  const int b    = blockIdx.x;

  const int* xr = x + b * L_;
  float* entOut = dout + (size_t)B_ * E_ + (size_t)b * L_;

  // ---------- Phase A: tokens -> LDS bytes; build tables ----------
  const int4 v0 = ((const int4*)xr)[2 * tid];
  const int4 v1 = ((const int4*)xr)[2 * tid + 1];
  unsigned pw0 = (unsigned)v0.x | ((unsigned)v0.y << 8) |
                 ((unsigned)v0.z << 16) | ((unsigned)v0.w << 24);
  unsigned pw1 = (unsigned)v1.x | ((unsigned)v1.y << 8) |
                 ((unsigned)v1.z << 16) | ((unsigned)v1.w << 24);
  *(uint2*)(tok8p + 8 + 8 * tid) = make_uint2(pw0, pw1);
  if (tid == 0) *(uint2*)(tok8p) = make_uint2(~0u, ~0u);
  if (tid == 1) *(uint2*)(tok8p + 8 + L_) = make_uint2(~0u, ~0u);
  if (tid < 100) {
    int a = tid / 10, c = tid - 10 * a;
    float pa = (float)a / 9.0f, pb = (float)c / 9.0f;
    float fa = -(pa * log2f(pa + 1e-12f));
    float fb = -(pb * log2f(pb + 1e-12f));
    pairTab[tid] = fa + fb;                      // f(0)=0 so f(e)=pairTab[10e]
  }
  if (tid >= 100 && tid < 113) {
    int n = tid - 100;
    rcpTab[n] = 1.0f / (float)(n == 0 ? 1 : n);
  }
  __syncthreads();

  // ---------- Phase B: sliding-window entropy, masks ----------
  // 24 token bytes covering global tokens 8t-8 .. 8t+15 (pads are 0xFF -> code 0)
  unsigned long long tw0 = *(const unsigned long long*)(tok8p + 8 * tid);
  unsigned long long tw1 = *(const unsigned long long*)(tok8p + 8 * tid + 8);
  unsigned long long tw2 = *(const unsigned long long*)(tok8p + 8 * tid + 16);
  unsigned code[20];                              // local idx l = g - (8t-8), use 4..19
  #pragma unroll
  for (int l = 4; l < 20; ++l) {
    unsigned byte = (l < 8)  ? (unsigned)((tw0 >> (8 * l)) & 0xff)
                  : (l < 16) ? (unsigned)((tw1 >> (8 * (l - 8))) & 0xff)
                             : (unsigned)((tw2 >> (8 * (l - 16))) & 0xff);
    code[l] = (byte <= 4u) ? (1u << (6 * byte)) : 0u;  // 5 counts in 6-bit fields
  }
  unsigned s = 0;
  #pragma unroll
  for (int l = 4; l <= 12; ++l) s += code[l];     // window of p = 8t
  float entv[PT];
  #pragma unroll
  for (int q = 0; q < PT; ++q) {
    if (q) s += code[q + 12] - code[q + 3];
    unsigned a  = s & 63u,        bb = (s >> 6) & 63u, cc = (s >> 12) & 63u;
    unsigned dd = (s >> 18) & 63u, ee = (s >> 24) & 63u;
    entv[q] = pairTab[a * 10u + bb] + pairTab[cc * 10u + dd] + pairTab[ee * 10u];
  }
  if (tid == 0 || tid == T_ - 1) {                // 8 clipped-window edge positions
    #pragma unroll
    for (int q = 0; q < PT; ++q) {
      int p = 8 * tid + q;
      if (p < 4 || p >= L_ - 4) {
        unsigned ss = 0;
        for (int l = q + 4; l <= q + 12; ++l) ss += code[l];
        unsigned cn[5] = { ss & 63u, (ss >> 6) & 63u, (ss >> 12) & 63u,
                           (ss >> 18) & 63u, (ss >> 24) & 63u };
        float rT = 1.0f / (float)(cn[0] + cn[1] + cn[2] + cn[3] + cn[4]);
        float ent = 0.f;
        for (int k2 = 0; k2 < 5; ++k2) {
          float pr = (float)cn[k2] * rT;
          ent -= pr * log2f(pr + 1e-12f);
        }
        entv[q] = ent;
      }
    }
  }
  ((float4*)entOut)[2 * tid]     = make_float4(entv[0], entv[1], entv[2], entv[3]);
  ((float4*)entOut)[2 * tid + 1] = make_float4(entv[4], entv[5], entv[6], entv[7]);
  unsigned mbyte = 0;
  #pragma unroll
  for (int q = 0; q < PT; ++q) mbyte |= (entv[q] > 1.5f ? 1u : 0u) << q;
  maskBytes[tid] = (unsigned char)mbyte;

  // ---------- Phase C: exclusive token prefix sums (exact ints in fp32) ----------
  int tk[8];
  #pragma unroll
  for (int j = 0; j < 4; ++j) {
    tk[j]     = (int)((pw0 >> (8 * j)) & 0xffu);
    tk[4 + j] = (int)((pw1 >> (8 * j)) & 0xffu);
  }
  int ls = tk[0] + tk[1] + tk[2] + tk[3] + tk[4] + tk[5] + tk[6] + tk[7];
  int incl = ls;
  #pragma unroll
  for (int d = 1; d < 64; d <<= 1) {
    int up = __shfl_up(incl, d, 64);
    if (lane >= d) incl += up;
  }
  if (lane == 63) waveTot[wv] = incl;
  __syncthreads();                                // publishes waveTot + maskBytes
  int base = 0;
  #pragma unroll
  for (int q = 0; q < 16; ++q) base += (q < wv) ? waveTot[q] : 0;
  float acc = (float)(base + incl - ls);
  {
    float4 c0, c1;
    c0.x = acc; acc += (float)tk[0]; c0.y = acc; acc += (float)tk[1];
    c0.z = acc; acc += (float)tk[2]; c0.w = acc; acc += (float)tk[3];
    c1.x = acc; acc += (float)tk[4]; c1.y = acc; acc += (float)tk[5];
    c1.z = acc; acc += (float)tk[6]; c1.w = acc; acc += (float)tk[7];
    ((float4*)csBuf)[2 * tid] = c0; ((float4*)csBuf)[2 * tid + 1] = c1;
    if (tid == T_ - 1) csBuf[L_] = acc;
  }

  // ---------- Phase D: per-(chunk, entry 0..11) exit walk, masks in VGPRs ----------
  unsigned long long m0 = 0, m1 = 0;
  if (tid < 768) {
    int c = tid & 63, o = tid >> 6;
    m0 = *(const unsigned long long*)(maskBytes + 16 * c);
    m1 = *(const unsigned long long*)(maskBytes + 16 * c + 8);
    int p = o;
    while (p < CHUNK) {
      unsigned long long mm = (p & 64) ? m1 : m0;
      p += ((mm >> (p & 63)) & 1ULL) ? 3 : 12;
    }
    exitT[c][o] = (unsigned char)(p - CHUNK);
  }
  __syncthreads();                                // exitT + csBuf ready

  // ---------- Compose exit maps (wave 0): packed 12x4-bit shuffle scan ----------
  int myOff = 0;
  if (tid < 64) {
    const unsigned* ep = (const unsigned*)&exitT[tid][0];  // stride 12 % 4 == 0
    unsigned u0 = ep[0], u1 = ep[1], u2 = ep[2];
    auto nib = [](unsigned w) {
      return (w & 0xFu) | ((w >> 4) & 0xF0u) | ((w >> 8) & 0xF00u) | ((w >> 12) & 0xF000u);
    };
    unsigned long long tab = (unsigned long long)nib(u0)
                           | ((unsigned long long)nib(u1) << 16)
                           | ((unsigned long long)nib(u2) << 32);
    #pragma unroll
    for (int d = 1; d < 64; d <<= 1) {
      unsigned long long other =
          (unsigned long long)__shfl_up((long long)tab, d, 64);
      if (lane >= d) {
        unsigned long long nt = 0;
        #pragma unroll
        for (int e = 0; e < 12; ++e) {
          unsigned oe  = (unsigned)((other >> (4 * e)) & 15ULL);
          unsigned val = (unsigned)((tab >> (4 * oe)) & 15ULL);
          nt |= (unsigned long long)val << (4 * e);
        }
        tab = nt;
      }
    }
    unsigned long long prev = (unsigned long long)__shfl_up((long long)tab, 1, 64);
    myOff = (lane == 0) ? 0 : (int)(prev & 15ULL);

    // ---------- Phase E: walk own chunk, emit patch means ----------
    int c = tid;
    int p = CHUNK * c + myOff;
    const int end = CHUNK * c + CHUNK;
    float csp = csBuf[p];
    int n = 0;
    while (p < end) {
      int lp = p - CHUNK * c;
      unsigned long long mm = (lp & 64) ? m1 : m0;
      int ps = ((mm >> (lp & 63)) & 1ULL) ? 3 : 12;
      int j = p + ps; if (j > L_) j = L_;
      float csj = csBuf[j];
      meanbuf[c][n++] = (csj - csp) * rcpTab[j - p];
      csp = csj; p = j;
    }
    cntC[c] = n;
    int tot = n;
    #pragma unroll
    for (int d2 = 32; d2; d2 >>= 1) tot += __shfl_xor(tot, d2, 64);
    if (lane == 0) PcountS = tot;
  }
  __syncthreads();

  // ---------- Phase F: S[e] = sum relu(mean*w1[e]+b1[e]) over patches ----------
  {
    const float w1v = w1[lane];
    const float b1v = b1[lane];
    float S = 0.0f;
    for (int c = wv; c < NCH; c += 16) {
      int n = cntC[c];
      const float* mb = &meanbuf[c][0];
      int j = 0;
      for (; j + 4 <= n; j += 4) {
        float4 m4 = *((const float4*)(mb + j));   // broadcast b128 read
        S += fmaxf(fmaf(m4.x, w1v, b1v), 0.0f);
        S += fmaxf(fmaf(m4.y, w1v, b1v), 0.0f);
        S += fmaxf(fmaf(m4.z, w1v, b1v), 0.0f);
        S += fmaxf(fmaf(m4.w, w1v, b1v), 0.0f);
      }
      for (; j < n; ++j) S += fmaxf(fmaf(mb[j], w1v, b1v), 0.0f);
    }
    Sred[wv][lane] = S;
  }
  __syncthreads();
  if (tid < 64) {
    float sm = 0.f;
    #pragma unroll
    for (int q = 0; q < 16; ++q) sm += Sred[q][tid];
    avgv[tid] = sm / (float)PcountS;
  }
  __syncthreads();

  // ---------- Phase G: tiny matvec out = avg @ w2^T + b2 ----------
  {
    float acc2 = 0.f;
    #pragma unroll
    for (int kk = 0; kk < 4; ++kk) {
      int k = 4 * wv + kk;
      acc2 = fmaf(avgv[k], w2[lane * 64 + k], acc2);
    }
    partG[wv][lane] = acc2;
  }
  __syncthreads();
  if (tid < 64) {
    float r = b2[tid];
    #pragma unroll
    for (int q = 0; q < 16; ++q) r += partG[q][tid];
    dout[(size_t)b * E_ + tid] = r;
  }
}

extern "C" void kernel_launch(void* const* d_in, const int* in_sizes, int n_in,
                              void* d_out, int out_size, void* d_ws, size_t ws_size,
                              hipStream_t stream) {
  const int*   x  = (const int*)d_in[0];
  const float* w1 = (const float*)d_in[1];
  const float* b1 = (const float*)d_in[2];
  const float* w2 = (const float*)d_in[3];
  const float* b2 = (const float*)d_in[4];
  float* out = (float*)d_out;
  entropy_patcher_kernel<<<B_, T_, 0, stream>>>(x, w1, b1, w2, b2, out);
}